// Round 8
// baseline (362.793 us; speedup 1.0000x reference)
//
#include <hip/hip_runtime.h>
#include <hip/hip_fp16.h>
#include <stdint.h>
#include <math.h>

// ProductMonoidHead — round 8 (= R7 resubmit; R7 never acquired a GPU).
// proj occupancy: 16-row/8-row tiles, 1024 blocks, 4 blocks/CU; wave roles =
// (product, cf) in proj_qk (no cross-wave combine); level-interleaved LDS
// swizzle in proj_v. Fused attn kernel unchanged from R6.
// B=8 N=M=1024 D=1024 MB=32 H=128.
// d_out = out[8192][128] f32 ++ attn[8192][1024] f32.

#define SCALE_F 0.17677669529663687f

typedef float4 f4;
typedef unsigned int uint_t;
typedef unsigned short ushort_t;
typedef __attribute__((ext_vector_type(8))) short s16x8;
typedef __attribute__((ext_vector_type(8))) unsigned short u16x8;
typedef __attribute__((ext_vector_type(4))) float f32x4;

__device__ __forceinline__ ushort_t f2bf(float x) {
    unsigned u = __float_as_uint(x);
    return (ushort_t)((u + 0x7FFFu + ((u >> 16) & 1u)) >> 16);
}
__device__ __forceinline__ float bf2f(ushort_t h) {
    return __uint_as_float(((unsigned)h) << 16);
}
__device__ __forceinline__ float f4c(const f4 v, int i) {
    return i == 0 ? v.x : (i == 1 ? v.y : (i == 2 ? v.z : v.w));
}
__device__ __forceinline__ unsigned pk_add(unsigned a, unsigned b) {
    unsigned r;
    asm("v_pk_add_f16 %0, %1, %2" : "=v"(r) : "v"(a), "v"(b));
    return r;
}
__device__ __forceinline__ unsigned pk_max(unsigned a, unsigned b) {
    unsigned r;
    asm("v_pk_max_f16 %0, %1, %2" : "=v"(r) : "v"(a), "v"(b));
    return r;
}
__device__ __forceinline__ float h2f(ushort_t u) {
    __half h;
    *reinterpret_cast<ushort_t*>(&h) = u;
    return __half2float(h);
}
__device__ __forceinline__ ushort_t f2h(float x) {
    __half h = __float2half(x);
    return *reinterpret_cast<ushort_t*>(&h);
}

#define MFMA16(a, b, c) __builtin_amdgcn_mfma_f32_16x16x32_bf16((a), (b), (c), 0, 0, 0)

// 64-K layout (proj_qk): swizzled read offset into [cols][64K] level array; kq in 0..7
__device__ __forceinline__ int bo(int col, int kq) {
    return col * 64 + 8 * (kq ^ (col & 7));
}
// linear fill slot s -> inverse-swizzled source k-offset (64-K layout)
__device__ __forceinline__ int fillk(int s) {
    return 8 * ((s & 7) ^ ((s >> 3) & 7));
}

// ---------------- conv_w (unchanged) ----------------
__global__ __launch_bounds__(256)
void conv_w_kernel(const float* __restrict__ Wqb, const float* __restrict__ Wkb,
                   const float* __restrict__ Wqt, const float* __restrict__ Wkt,
                   const float* __restrict__ Wqr, const float* __restrict__ Wkr,
                   const float* __restrict__ Wv,
                   ushort_t* __restrict__ Wh, ushort_t* __restrict__ Wm,
                   ushort_t* __restrict__ Wl3,
                   ushort_t* __restrict__ Wvh, ushort_t* __restrict__ Wvm) {
    __shared__ float T[256][33];
    const int t = threadIdx.x;
    const int bid = blockIdx.x;
    const float* src;
    int kb, outRowBase, srcStride, srcColBase, side = 0;
    bool isQK, isBool;
    if (bid < 24) {
        side = bid / 12;
        int cb = (bid % 12) / 4;
        kb = bid & 3;
        const float* mats[6] = {Wqb, Wqt, Wqr, Wkb, Wkt, Wkr};
        src = mats[side * 3 + cb];
        srcStride = 32; srcColBase = 0;
        outRowBase = side * 96 + cb * 32;
        isQK = true; isBool = (cb == 0);
    } else {
        int v = bid - 24;
        int hb = v >> 2; kb = v & 3;
        src = Wv; srcStride = 128; srcColBase = hb * 32;
        outRowBase = hb * 32;
        isQK = false; isBool = false;
    }
    #pragma unroll
    for (int i = 0; i < 8; ++i) {
        int idx = t + i * 256;
        int r = idx >> 3, c4 = idx & 7;
        f4 v = *(const f4*)&src[(size_t)(kb * 256 + r) * srcStride + srcColBase + c4 * 4];
        T[r][c4 * 4 + 0] = v.x; T[r][c4 * 4 + 1] = v.y;
        T[r][c4 * 4 + 2] = v.z; T[r][c4 * 4 + 3] = v.w;
    }
    __syncthreads();
    const int col = t >> 3, kseg = t & 7;
    ushort_t* dh = isQK ? Wh : Wvh;
    ushort_t* dm = isQK ? Wm : Wvm;
    size_t obase = (size_t)(outRowBase + col) * 1024 + kb * 256 + kseg * 32;
    u16x8 ph[4], pm[4], pl[4];
    #pragma unroll
    for (int i = 0; i < 32; ++i) {
        float x = T[kseg * 32 + i][col];
        ushort_t hb_ = f2bf(x);
        float r1 = x - bf2f(hb_);
        ushort_t mb_ = f2bf(r1);
        float r2 = r1 - bf2f(mb_);
        ph[i >> 3][i & 7] = hb_;
        pm[i >> 3][i & 7] = mb_;
        pl[i >> 3][i & 7] = f2bf(r2);
    }
    #pragma unroll
    for (int i = 0; i < 4; ++i) {
        *(u16x8*)&dh[obase + i * 8] = ph[i];
        *(u16x8*)&dm[obase + i * 8] = pm[i];
    }
    if (isBool) {
        size_t lbase = (size_t)(side * 32 + col) * 1024 + kb * 256 + kseg * 32;
        #pragma unroll
        for (int i = 0; i < 4; ++i) *(u16x8*)&Wl3[lbase + i * 8] = pl[i];
    }
}

// ---------------- proj_qk: 16-row tiles x 1024 blocks, wave = (product, cf) ----------------

__global__ __launch_bounds__(256, 4)
void proj_qk_kernel(const float* __restrict__ Q, const float* __restrict__ K,
                    const ushort_t* __restrict__ Wh, const ushort_t* __restrict__ Wm,
                    ushort_t* __restrict__ Qt_q, ushort_t* __restrict__ Kt_q,
                    ushort_t* __restrict__ Qrh, ushort_t* __restrict__ Qrm,
                    ushort_t* __restrict__ Krh, ushort_t* __restrict__ Krm,
                    uint_t* __restrict__ Qbits, uint_t* __restrict__ Kbits) {
    __shared__ ushort_t POOL[20480];               // 40960 B exactly -> 4 blocks/CU
    ushort_t* BH = POOL;                           // [2][6144]
    ushort_t* BM = POOL + 12288;                   // [2][4096]
    const int t = threadIdx.x, lane = t & 63, w = t >> 6;
    const int g = lane >> 4, l15 = lane & 15;
    const int side = blockIdx.x >> 9;
    const int tile = blockIdx.x & 511;
    const int row0 = tile * 16;
    const bool isBool = (w < 2);
    const int cf = w & 1;
    const float* __restrict__ X = side ? K : Q;
    const float* __restrict__ Xrow = X + (size_t)(row0 + l15) * 1024;

    const ushort_t* srcH[3]; int dstH[3];
    #pragma unroll
    for (int i = 0; i < 3; ++i) {
        int s = t + i * 256;
        int col = s >> 3;
        srcH[i] = Wh + (size_t)(side * 96 + col) * 1024 + fillk(s);
        dstH[i] = s * 8;
    }
    const ushort_t* srcM[2]; int dstM[2];
    #pragma unroll
    for (int i = 0; i < 2; ++i) {
        int s = t + i * 256;
        int col = s >> 3;
        int f = (col < 32) ? col : col + 32;
        srcM[i] = Wm + (size_t)(side * 96 + f) * 1024 + fillk(s);
        dstM[i] = s * 8;
    }

    // w0/w1: accA = bool accumulator (cols cf*16+l15)
    // w2/w3: accA = trop, accC = real
    f32x4 accA = f32x4{0.f, 0.f, 0.f, 0.f};
    f32x4 accC = f32x4{0.f, 0.f, 0.f, 0.f};

    f4 arE[4], arO[4];
    u16x8 hE[3], mE[2], hO[3], mO[2];

    auto STAGE_A = [&](int k0, f4* ar) {
        ar[0] = *(const f4*)&Xrow[k0 + g * 8];
        ar[1] = *(const f4*)&Xrow[k0 + g * 8 + 4];
        ar[2] = *(const f4*)&Xrow[k0 + 32 + g * 8];
        ar[3] = *(const f4*)&Xrow[k0 + 32 + g * 8 + 4];
    };
    auto STAGE_B = [&](int k0, u16x8* hh, u16x8* mm) {
        #pragma unroll
        for (int i = 0; i < 3; ++i) hh[i] = *(const u16x8*)(srcH[i] + k0);
        #pragma unroll
        for (int i = 0; i < 2; ++i) mm[i] = *(const u16x8*)(srcM[i] + k0);
    };
    auto WRITE_B = [&](int buf, u16x8* hh, u16x8* mm) {
        #pragma unroll
        for (int i = 0; i < 3; ++i) *(u16x8*)&BH[buf * 6144 + dstH[i]] = hh[i];
        #pragma unroll
        for (int i = 0; i < 2; ++i) *(u16x8*)&BM[buf * 4096 + dstM[i]] = mm[i];
    };
    auto COMPUTE = [&](int buf, f4* ar) {
        #pragma unroll
        for (int ks = 0; ks < 2; ++ks) {
            u16x8 ah, am, al;
            #pragma unroll
            for (int j = 0; j < 8; ++j) {
                float x = (j < 4) ? f4c(ar[2 * ks], j) : f4c(ar[2 * ks + 1], j - 4);
                ushort_t hb_ = f2bf(x);
                float r1 = x - bf2f(hb_);
                ushort_t mb_ = f2bf(r1);
                ah[j] = hb_; am[j] = mb_;
                al[j] = f2bf(r1 - bf2f(mb_));
            }
            s16x8 a1 = (s16x8)ah, a2 = (s16x8)am;
            const int kq = ks * 4 + g;
            if (isBool) {                              // bool, 5-product, cols cf*16..
                s16x8 a3 = (s16x8)al;
                int col = cf * 16 + l15;
                s16x8 bh = *(const s16x8*)&BH[buf * 6144 + bo(col, kq)];
                s16x8 bm = *(const s16x8*)&BM[buf * 4096 + bo(col, kq)];
                accA = MFMA16(a1, bh, accA);
                accA = MFMA16(a1, bm, accA);
                accA = MFMA16(a2, bh, accA);
                accA = MFMA16(a2, bm, accA);
                accA = MFMA16(a3, bh, accA);
            } else {                                   // trop (1) + real (3)
                int colT = 32 + cf * 16 + l15;
                s16x8 bhT = *(const s16x8*)&BH[buf * 6144 + bo(colT, kq)];
                accA = MFMA16(a1, bhT, accA);
                int colh = 64 + cf * 16 + l15;
                int colm = 32 + cf * 16 + l15;
                s16x8 bh = *(const s16x8*)&BH[buf * 6144 + bo(colh, kq)];
                s16x8 bm = *(const s16x8*)&BM[buf * 4096 + bo(colm, kq)];
                accC = MFMA16(a1, bh, accC);
                accC = MFMA16(a1, bm, accC);
                accC = MFMA16(a2, bh, accC);
            }
        }
    };

    STAGE_A(0, arE);
    STAGE_B(0, hE, mE);
    WRITE_B(0, hE, mE);
    __syncthreads();
    for (int cc = 0; cc < 8; ++cc) {
        const int kE = cc * 128;
        STAGE_A(kE + 64, arO);
        STAGE_B(kE + 64, hO, mO);
        COMPUTE(0, arE);
        WRITE_B(1, hO, mO);
        __syncthreads();
        if (cc < 7) {
            STAGE_A(kE + 128, arE);
            STAGE_B(kE + 128, hE, mE);
        }
        COMPUTE(1, arO);
        if (cc < 7) WRITE_B(0, hE, mE);
        __syncthreads();
    }

    // epilogue: sb aliased over dead B buffers
    uint_t* sbp = (uint_t*)POOL;
    if (t < 32) sbp[t] = 0;
    __syncthreads();
    if (isBool) {
        #pragma unroll
        for (int r = 0; r < 4; ++r) {
            unsigned long long bm = __ballot(accA[r] > 0.f);
            if (lane == 0) {
                #pragma unroll
                for (int gg = 0; gg < 4; ++gg)
                    sbp[cf * 16 + gg * 4 + r] =
                        (uint_t)((bm >> (16 * gg)) & 0xFFFFull) << (16 * cf);
            }
        }
    } else {
        ushort_t* Tt = side ? Kt_q : Qt_q;
        ushort_t* Rh = side ? Krh : Qrh;
        ushort_t* Rm = side ? Krm : Qrm;
        #pragma unroll
        for (int r = 0; r < 4; ++r) {
            int grow = row0 + 4 * g + r;
            Tt[(size_t)grow * 32 + cf * 16 + l15] = f2h(accA[r]);
            float v = accC[r];
            ushort_t h = f2bf(v);
            Rh[(size_t)grow * 32 + cf * 16 + l15] = h;
            Rm[(size_t)grow * 32 + cf * 16 + l15] = f2bf(v - bf2f(h));
        }
    }
    __syncthreads();
    uint_t* Tb = side ? Kbits : Qbits;
    if (t < 16) Tb[row0 + t] = sbp[t] | sbp[16 + t];
}

// ---------------- proj_v: 8-row tiles x 1024 blocks, 32-K chunks, lvl-interleaved LDS ----------------
// LDS layout per buffer: col c occupies 64 ushorts (128 B): two 32-ushort halves;
// half hp holds level (hp ^ (c&1)); within a half, slot q holds kq = q ^ ((c>>1)&3).
// Read addr(c, lvl, g) = c*64 + (lvl^(c&1))*32 + 8*(g ^ ((c>>1)&3))  -> 2-way max.

__global__ __launch_bounds__(256, 4)
void proj_v_kernel(const float* __restrict__ V,
                   const ushort_t* __restrict__ Wvh, const ushort_t* __restrict__ Wvm,
                   ushort_t* __restrict__ VphT, ushort_t* __restrict__ VpmT) {
    __shared__ ushort_t PL[2][8192];               // 32768 B
    const int t = threadIdx.x, lane = t & 63, w = t >> 6;
    const int g = lane >> 4, l15 = lane & 15;
    const int tile = blockIdx.x;
    const int row0 = tile * 8;
    const int hbase = w * 32;
    const float* __restrict__ Xrow = V + (size_t)(row0 + (l15 & 7)) * 1024;

    const ushort_t* srcV[4]; int dstV[4];
    #pragma unroll
    for (int i = 0; i < 4; ++i) {
        int s = t + i * 256;
        int c = s >> 3, p8 = s & 7;
        int hp = p8 >> 2, q = p8 & 3;
        int lvl = hp ^ (c & 1);
        int kq = q ^ ((c >> 1) & 3);
        srcV[i] = (lvl ? Wvm : Wvh) + (size_t)c * 1024 + kq * 8;
        dstV[i] = s * 8;
    }

    f32x4 acc[2];
    acc[0] = f32x4{0.f, 0.f, 0.f, 0.f};
    acc[1] = f32x4{0.f, 0.f, 0.f, 0.f};

    f4 arE[2], arO[2];
    u16x8 vE[4], vO[4];

    auto STAGE_A = [&](int k0, f4* ar) {
        ar[0] = *(const f4*)&Xrow[k0 + g * 8];
        ar[1] = *(const f4*)&Xrow[k0 + g * 8 + 4];
    };
    auto STAGE_B = [&](int k0, u16x8* vv) {
        #pragma unroll
        for (int i = 0; i < 4; ++i) vv[i] = *(const u16x8*)(srcV[i] + k0);
    };
    auto WRITE_B = [&](int buf, u16x8* vv) {
        #pragma unroll
        for (int i = 0; i < 4; ++i) *(u16x8*)&PL[buf][dstV[i]] = vv[i];
    };
    auto COMPUTE = [&](int buf, f4* ar) {
        u16x8 ah, am;
        #pragma unroll
        for (int j = 0; j < 8; ++j) {
            float x = (j < 4) ? f4c(ar[0], j) : f4c(ar[1], j - 4);
            ushort_t hb_ = f2bf(x);
            ah[j] = hb_; am[j] = f2bf(x - bf2f(hb_));
        }
        s16x8 a1 = (s16x8)ah, a2 = (s16x8)am;
        #pragma unroll
        for (int cfi = 0; cfi < 2; ++cfi) {
            int c = hbase + cfi * 16 + l15;
            int sw = 8 * (g ^ ((c >> 1) & 3));
            int aH = c * 64 + ((0 ^ (c & 1)) * 32) + sw;
            int aM = c * 64 + ((1 ^ (c & 1)) * 32) + sw;
            s16x8 bh = *(const s16x8*)&PL[buf][aH];
            s16x8 bm = *(const s16x8*)&PL[buf][aM];
            acc[cfi] = MFMA16(a1, bh, acc[cfi]);
            acc[cfi] = MFMA16(a1, bm, acc[cfi]);
            acc[cfi] = MFMA16(a2, bh, acc[cfi]);
        }
    };

    STAGE_A(0, arE);
    STAGE_B(0, vE);
    WRITE_B(0, vE);
    __syncthreads();
    for (int cc2 = 0; cc2 < 16; ++cc2) {
        const int k = cc2 * 64;
        STAGE_A(k + 32, arO);
        STAGE_B(k + 32, vO);
        COMPUTE(0, arE);
        WRITE_B(1, vO);
        __syncthreads();
        if (cc2 < 15) {
            STAGE_A(k + 64, arE);
            STAGE_B(k + 64, vE);
        }
        COMPUTE(1, arO);
        if (cc2 < 15) WRITE_B(0, vE);
        __syncthreads();
    }

    // epilogue: rows 0..7 live in g<2 fragments; transposed ushort4 stores
    if (g < 2) {
        const int b = tile >> 7;
        const int mb = (tile & 127) * 8 + 4 * g;
        #pragma unroll
        for (int cfi = 0; cfi < 2; ++cfi) {
            int colh = hbase + cfi * 16 + l15;
            float v0 = acc[cfi][0], v1 = acc[cfi][1], v2 = acc[cfi][2], v3 = acc[cfi][3];
            ushort_t h0 = f2bf(v0), h1 = f2bf(v1), h2_ = f2bf(v2), h3 = f2bf(v3);
            ushort4 hv = make_ushort4(h0, h1, h2_, h3);
            ushort4 mv = make_ushort4(f2bf(v0 - bf2f(h0)), f2bf(v1 - bf2f(h1)),
                                      f2bf(v2 - bf2f(h2_)), f2bf(v3 - bf2f(h3)));
            size_t ob = (size_t)(b * 128 + colh) * 1024 + mb;
            *(ushort4*)&VphT[ob] = hv;
            *(ushort4*)&VpmT[ob] = mv;
        }
    }
}

// ---------------- fused: scores -> softmax -> attn write + PV (unchanged from R6) ----------------

#define SW 1036   // S row stride in uints (bank-skewed)

__global__ __launch_bounds__(256)
void fused_attn_kernel(const ushort_t* __restrict__ Qt_q, const ushort_t* __restrict__ Kt_q,
                       const ushort_t* __restrict__ Qrh, const ushort_t* __restrict__ Qrm,
                       const ushort_t* __restrict__ Krh, const ushort_t* __restrict__ Krm,
                       const uint_t* __restrict__ Qbits, const uint_t* __restrict__ Kbits,
                       const ushort_t* __restrict__ VphT, const ushort_t* __restrict__ VpmT,
                       const int* __restrict__ mask, const float* __restrict__ fw,
                       float* __restrict__ attn, float* __restrict__ out) {
    __shared__ uint_t S[16][SW];
    __shared__ float rmaxS[16], rinvS[16];
    const int t = threadIdx.x, lane = t & 63, w = t >> 6;
    const int g = lane >> 4, l15 = lane & 15;
    const int bid = blockIdx.x;
    const int b = bid & 7, n0 = (bid >> 3) * 16;   // XCD-local batch mapping
    const int rowA = b * 1024 + n0;

    s16x8 qrh = *(const s16x8*)&Qrh[(size_t)(rowA + l15) * 32 + g * 8];
    s16x8 qrm = *(const s16x8*)&Qrm[(size_t)(rowA + l15) * 32 + g * 8];
    uint_t qt[4][16], qb[4];
    #pragma unroll
    for (int r = 0; r < 4; ++r) {
        const uint_t* p = (const uint_t*)&Qt_q[(size_t)(rowA + 4 * g + r) * 32];
        #pragma unroll
        for (int j = 0; j < 16; ++j) qt[r][j] = p[j];
        qb[r] = Qbits[rowA + 4 * g + r];
    }
    const float f0 = fw[0], f1 = fw[1], f2 = fw[2];
    const float fm = fmaxf(f0, fmaxf(f1, f2));
    const float e0 = __expf(f0 - fm), e1 = __expf(f1 - fm), e2 = __expf(f2 - fm);
    const float wi = 1.f / (e0 + e1 + e2);
    const float w0 = e0 * wi, w1 = e1 * wi, w2 = e2 * wi;

    for (int i = 0; i < 16; ++i) {
        const int m0 = (w + 4 * i) * 16;
        const int mrow = b * 1024 + m0;
        const uint_t* ktp = (const uint_t*)&Kt_q[(size_t)(mrow + l15) * 32];
        uint_t kk[16];
        uint4 k0v = *(const uint4*)&ktp[0];
        uint4 k1v = *(const uint4*)&ktp[4];
        uint4 k2v = *(const uint4*)&ktp[8];
        uint4 k3v = *(const uint4*)&ktp[12];
        kk[0] = k0v.x; kk[1] = k0v.y; kk[2] = k0v.z; kk[3] = k0v.w;
        kk[4] = k1v.x; kk[5] = k1v.y; kk[6] = k1v.z; kk[7] = k1v.w;
        kk[8] = k2v.x; kk[9] = k2v.y; kk[10] = k2v.z; kk[11] = k2v.w;
        kk[12] = k3v.x; kk[13] = k3v.y; kk[14] = k3v.z; kk[15] = k3v.w;
        s16x8 krh = *(const s16x8*)&Krh[(size_t)(mrow + l15) * 32 + g * 8];
        s16x8 krm = *(const s16x8*)&Krm[(size_t)(mrow + l15) * 32 + g * 8];
        uint_t kb = Kbits[mrow + l15];
        int mk[4];
        #pragma unroll
        for (int r = 0; r < 4; ++r)
            mk[r] = mask[(size_t)(rowA + 4 * g + r) * 1024 + m0 + l15];

        f32x4 rc = f32x4{0.f, 0.f, 0.f, 0.f};
        rc = MFMA16(qrh, krh, rc);
        rc = MFMA16(qrh, krm, rc);
        rc = MFMA16(qrm, krh, rc);

        float trop[4];
        #pragma unroll
        for (int r = 0; r < 4; ++r) {
            unsigned a = pk_add(qt[r][0], kk[0]);
            #pragma unroll
            for (int j = 1; j < 16; ++j)
                a = pk_max(a, pk_add(qt[r][j], kk[j]));
            trop[r] = fmaxf(h2f((ushort_t)(a & 0xFFFF)), h2f((ushort_t)(a >> 16)));
        }
        #pragma unroll
        for (int r = 0; r < 4; ++r) {
            float cnt = (float)(32 - __popc(qb[r] ^ kb));
            float s = (w0 * cnt + w1 * trop[r] + w2 * rc[r]) * SCALE_F;
            *(float*)&S[4 * g + r][m0 + l15] = mk[r] ? s : -INFINITY;
        }
    }
    __syncthreads();

    #pragma unroll
    for (int q = 0; q < 4; ++q) {
        const int row = 4 * w + q;
        float mx = -INFINITY;
        #pragma unroll
        for (int j = 0; j < 16; ++j)
            mx = fmaxf(mx, *(const float*)&S[row][lane + j * 64]);
        #pragma unroll
        for (int off = 32; off >= 1; off >>= 1) mx = fmaxf(mx, __shfl_xor(mx, off, 64));
        float sm = 0.f;
        #pragma unroll
        for (int j = 0; j < 16; ++j)
            sm += __expf(*(const float*)&S[row][lane + j * 64] - mx);
        #pragma unroll
        for (int off = 32; off >= 1; off >>= 1) sm += __shfl_xor(sm, off, 64);
        if (lane == 0) { rmaxS[row] = mx; rinvS[row] = 1.f / sm; }
    }
    __syncthreads();

    #pragma unroll
    for (int j = 0; j < 16; ++j) {
        const float mx = rmaxS[j], inv = rinvS[j];
        f4 s4 = *(const f4*)&S[j][t * 4];
        float p0 = __expf(s4.x - mx) * inv;
        float p1 = __expf(s4.y - mx) * inv;
        float p2 = __expf(s4.z - mx) * inv;
        float p3 = __expf(s4.w - mx) * inv;
        *(f4*)&attn[(size_t)(rowA + j) * 1024 + t * 4] = make_float4(p0, p1, p2, p3);
        ushort_t h0 = f2bf(p0), h1 = f2bf(p1), h2_ = f2bf(p2), h3 = f2bf(p3);
        uint4 pk;
        pk.x = (uint_t)h0 | ((uint_t)f2bf(p0 - bf2f(h0)) << 16);
        pk.y = (uint_t)h1 | ((uint_t)f2bf(p1 - bf2f(h1)) << 16);
        pk.z = (uint_t)h2_ | ((uint_t)f2bf(p2 - bf2f(h2_)) << 16);
        pk.w = (uint_t)h3 | ((uint_t)f2bf(p3 - bf2f(h3)) << 16);
        *(uint4*)&S[j][t * 4] = pk;
    }
    __syncthreads();

    const int hbase = w * 32;
    f32x4 acc[2];
    acc[0] = f32x4{0.f, 0.f, 0.f, 0.f};
    acc[1] = f32x4{0.f, 0.f, 0.f, 0.f};
    for (int mc = 0; mc < 32; ++mc) {
        const int m0 = mc * 32;
        uint4 ua = *(const uint4*)&S[l15][m0 + g * 8];
        uint4 ub = *(const uint4*)&S[l15][m0 + g * 8 + 4];
        u16x8 a1v, a2v;
        uint_t uu[8] = {ua.x, ua.y, ua.z, ua.w, ub.x, ub.y, ub.z, ub.w};
        #pragma unroll
        for (int j = 0; j < 8; ++j) {
            a1v[j] = (ushort_t)(uu[j] & 0xFFFFu);
            a2v[j] = (ushort_t)(uu[j] >> 16);
        }
        s16x8 a1 = (s16x8)a1v, a2 = (s16x8)a2v;
        #pragma unroll
        for (int cfi = 0; cfi < 2; ++cfi) {
            const size_t vb = (size_t)(b * 128 + hbase + cfi * 16 + l15) * 1024 + m0 + g * 8;
            s16x8 bh = *(const s16x8*)&VphT[vb];
            s16x8 bm = *(const s16x8*)&VpmT[vb];
            acc[cfi] = MFMA16(a1, bh, acc[cfi]);
            acc[cfi] = MFMA16(a1, bm, acc[cfi]);
            acc[cfi] = MFMA16(a2, bh, acc[cfi]);
        }
    }
    #pragma unroll
    for (int cfi = 0; cfi < 2; ++cfi)
        #pragma unroll
        for (int r = 0; r < 4; ++r)
            out[(size_t)(rowA + 4 * g + r) * 128 + hbase + cfi * 16 + l15] = acc[cfi][r];
}

// ---------------- launch ----------------

extern "C" void kernel_launch(void* const* d_in, const int* in_sizes, int n_in,
                              void* d_out, int out_size, void* d_ws, size_t ws_size,
                              hipStream_t stream) {
    const float* Q   = (const float*)d_in[0];
    const float* K   = (const float*)d_in[1];
    const float* V   = (const float*)d_in[2];
    const float* Wqb = (const float*)d_in[3];
    const float* Wkb = (const float*)d_in[4];
    const float* Wqt = (const float*)d_in[5];
    const float* Wkt = (const float*)d_in[6];
    const float* Wqr = (const float*)d_in[7];
    const float* Wkr = (const float*)d_in[8];
    const float* Wv  = (const float*)d_in[9];
    const float* fw  = (const float*)d_in[10];
    const int*  mask = (const int*)d_in[11];

    ushort_t* wsu = (ushort_t*)d_ws;
    ushort_t* Wh   = wsu;              // [192][1024]
    ushort_t* Wm   = Wh + 196608;
    ushort_t* Wl3  = Wm + 196608;      // [64][1024] (conv_w writes; unused downstream)
    ushort_t* Wvh  = Wl3 + 65536;      // [128][1024]
    ushort_t* Wvm  = Wvh + 131072;
    ushort_t* Qt_q = Wvm + 131072;     // [8192][32] f16 trop codes
    ushort_t* Kt_q = Qt_q + 262144;
    ushort_t* Qrh  = Kt_q + 262144;    // [8192][32] bf16 hi/mid real codes
    ushort_t* Qrm  = Qrh + 262144;
    ushort_t* Krh  = Qrm + 262144;
    ushort_t* Krm  = Krh + 262144;
    ushort_t* VphT = Krm + 262144;     // [8*128][1024] bf16 hi/mid (transposed)
    ushort_t* VpmT = VphT + 1048576;
    uint_t* Qbits = (uint_t*)(VpmT + 1048576);
    uint_t* Kbits = Qbits + 8192;

    float* out  = (float*)d_out;       // [8192][128]
    float* attn = out + 1048576;       // [8192][1024]

    conv_w_kernel<<<40, 256, 0, stream>>>(Wqb, Wkb, Wqt, Wkt, Wqr, Wkr, Wv,
                                          Wh, Wm, Wl3, Wvh, Wvm);
    proj_qk_kernel<<<1024, 256, 0, stream>>>(Q, K, Wh, Wm,
                                             Qt_q, Kt_q, Qrh, Qrm, Krh, Krm, Qbits, Kbits);
    proj_v_kernel<<<1024, 256, 0, stream>>>(V, Wvh, Wvm, VphT, VpmT);
    fused_attn_kernel<<<512, 256, 0, stream>>>(Qt_q, Kt_q, Qrh, Qrm, Krh, Krm,
                                               Qbits, Kbits, VphT, VpmT,
                                               mask, fw, attn, out);
}